// Round 9
// baseline (97.852 us; speedup 1.0000x reference)
//
#include <hip/hip_runtime.h>
#include <hip/hip_bf16.h>

// out[b,w] = relu(sqrt(max(||x_b||^2 + ||w_w||^2 - 2*x_b.w_w, 0)) / sqrt(512))
// M=8192, N=4096, K=512. bf16 MFMA NT-GEMM.
// R6 structure (128x128 tile, BK=64, 4 waves, 2 barriers/K-step, T2 swizzle
// on B) + ONE change: A is NOT staged in LDS. A fragments are loaded directly
// global->VGPR (16-B/lane, 64-B row segments, L1/L2-resident panel), issued
// with the B-stage glls so the barrier drain lands them for free. LDS read
// traffic per wave per K-step: 16 KB -> 8 KB (B only) — tests the measured
// LDS-BW-bound model (192 KB/CU/step == 112 B/cyc budget match).

typedef __bf16 bf16x8 __attribute__((ext_vector_type(8)));
typedef float f32x4 __attribute__((ext_vector_type(4)));

#define K_DIM 512
#define INV_SCALE 0.04419417382415922f  // 1/22.627417

__device__ __forceinline__ ushort f2bf(float f) {
  __hip_bfloat16 h = __float2bfloat16(f);
  return __builtin_bit_cast(ushort, h);
}

// fp32 -> bf16 convert + row sum of squares. One 128-thread block per row.
__global__ __launch_bounds__(128) void convert_kernel(
    const float* __restrict__ x, const float* __restrict__ w,
    ushort* __restrict__ xb, ushort* __restrict__ wb,
    float* __restrict__ xsq, float* __restrict__ wsq, int M) {
  int b = blockIdx.x;
  const float* src; ushort* dst; float* sq; int row;
  if (b < M) { src = x; dst = xb; sq = xsq; row = b; }
  else       { src = w; dst = wb; sq = wsq; row = b - M; }
  int t = threadIdx.x;
  float4 v = reinterpret_cast<const float4*>(src + (size_t)row * K_DIM)[t];
  ushort4 p;
  p.x = f2bf(v.x); p.y = f2bf(v.y); p.z = f2bf(v.z); p.w = f2bf(v.w);
  reinterpret_cast<ushort4*>(dst + (size_t)row * K_DIM)[t] = p;
  float s = v.x * v.x + v.y * v.y + v.z * v.z + v.w * v.w;
#pragma unroll
  for (int o = 32; o > 0; o >>= 1) s += __shfl_down(s, o, 64);
  __shared__ float red[2];
  if ((t & 63) == 0) red[t >> 6] = s;
  __syncthreads();
  if (t == 0) sq[row] = red[0] + red[1];
}

// B LDS holds (row, ch) = global(row, ch ^ (row&7)); staging pre-swizzles the
// per-lane global source chunk (linear gll dest), reads XOR with row&7.
__global__ void gemm_dist_kernel(
    const ushort* __restrict__ xb, const ushort* __restrict__ wb,
    const float* __restrict__ xsq, const float* __restrict__ wsq,
    float* __restrict__ out, int M, int N) {
  __shared__ ushort Bsm[128 * 64];  // 16 KB (B only)

  const int ntN = N >> 7;
  const int nwg = gridDim.x;
  const int bid = blockIdx.x;
  const int swz = ((nwg & 7) == 0) ? ((bid & 7) * (nwg >> 3) + (bid >> 3)) : bid;
  const int tR = swz / ntN;
  const int tC = swz - tR * ntN;

  const int tid = threadIdx.x;
  const int wid = tid >> 6;
  const int lane = tid & 63;
  const int wr = wid >> 1, wc = wid & 1;
  const int l15 = lane & 15, l4 = lane >> 4;

  const int rowA0 = tR << 7;
  const int rowB0 = tC << 7;

  f32x4 acc[4][4] = {};

  // B staging map (R6): wave wid covers tile rows [wid*32,+32) in 4 calls of
  // 8 rows; lane l -> row +(l>>3), source chunk pre-swizzled (l&7)^(l>>3).
  const int srow = (wid << 5) + (lane >> 3);
  const int scol = ((lane & 7) ^ (lane >> 3)) << 3;
  const ushort* gB = wb + (size_t)(rowB0 + srow) * K_DIM + scol;

  // A direct-load base: frag (i,kk): row rowA0 + wr*64 + i*16 + l15,
  // col kt + kk*32 + l4*8. Per wave-inst: 16 rows x 64 contiguous bytes.
  const ushort* gA = xb + (size_t)(rowA0 + (wr << 6) + l15) * K_DIM + (l4 << 3);

  const int axor = l15 & 7;  // row&7 for this lane's B fragment rows

  for (int kt = 0; kt < K_DIM; kt += 64) {
#pragma unroll
    for (int c = 0; c < 4; ++c) {
      const int r0 = (wid << 5) + (c << 3);  // wave-uniform LDS row base
      __builtin_amdgcn_global_load_lds(
          (const __attribute__((address_space(1))) void*)(gB + (size_t)(c * 8) * K_DIM + kt),
          (__attribute__((address_space(3))) void*)&Bsm[r0 * 64], 16, 0, 0);
    }
    // A fragments for this K-step: 8 direct global loads into regs.
    bf16x8 afr[2][4];
#pragma unroll
    for (int kk = 0; kk < 2; ++kk)
#pragma unroll
      for (int i = 0; i < 4; ++i)
        afr[kk][i] = *reinterpret_cast<const bf16x8*>(
            gA + (size_t)(i * 16) * K_DIM + kt + (kk << 5));
    __syncthreads();  // drains vmcnt(0): B in LDS, A in regs

#pragma unroll
    for (int kk = 0; kk < 2; ++kk) {
      bf16x8 bfr[4];
      const int cx = (((kk << 2) + l4) ^ axor) << 3;  // swizzled chunk offset
#pragma unroll
      for (int j = 0; j < 4; ++j)
        bfr[j] = *reinterpret_cast<const bf16x8*>(
            &Bsm[((wc << 6) + (j << 4) + l15) * 64 + cx]);
#pragma unroll
      for (int i = 0; i < 4; ++i)
#pragma unroll
        for (int j = 0; j < 4; ++j)
          acc[i][j] = __builtin_amdgcn_mfma_f32_16x16x32_bf16(
              afr[kk][i], bfr[j], acc[i][j], 0, 0, 0);
    }
    __syncthreads();  // B slot consumed, safe to overwrite next step
  }

  // Epilogue (R6 exact). C/D mapping: col = lane&15, row = (lane>>4)*4 + reg.
  const int colBase = rowB0 + (wc << 6) + l15;
  const int rowBase = rowA0 + (wr << 6) + (l4 << 2);
  float xq[4][4];
#pragma unroll
  for (int i = 0; i < 4; ++i)
#pragma unroll
    for (int r = 0; r < 4; ++r) xq[i][r] = xsq[rowBase + (i << 4) + r];
  float wq[4];
#pragma unroll
  for (int j = 0; j < 4; ++j) wq[j] = wsq[colBase + (j << 4)];

#pragma unroll
  for (int i = 0; i < 4; ++i) {
#pragma unroll
    for (int r = 0; r < 4; ++r) {
      const size_t rbase = (size_t)(rowBase + (i << 4) + r) * (size_t)N;
#pragma unroll
      for (int j = 0; j < 4; ++j) {
        float v = xq[i][r] + wq[j] - 2.0f * acc[i][j][r];
        v = fmaxf(v, 0.0f);
        out[rbase + colBase + (j << 4)] = sqrtf(v) * INV_SCALE;
      }
    }
  }
}

extern "C" void kernel_launch(void* const* d_in, const int* in_sizes, int n_in,
                              void* d_out, int out_size, void* d_ws, size_t ws_size,
                              hipStream_t stream) {
  const float* x = (const float*)d_in[0];   // (M, 512) fp32
  const float* w = (const float*)d_in[1];   // (N, 512) fp32
  const int M = in_sizes[0] / K_DIM;        // 8192
  const int N = in_sizes[1] / K_DIM;        // 4096
  float* out = (float*)d_out;

  char* ws = (char*)d_ws;
  ushort* xb = (ushort*)ws;
  ushort* wb = (ushort*)(ws + (size_t)M * K_DIM * 2);
  float* xsq = (float*)(ws + (size_t)M * K_DIM * 2 + (size_t)N * K_DIM * 2);
  float* wsq = xsq + M;

  convert_kernel<<<M + N, 128, 0, stream>>>(x, w, xb, wb, xsq, wsq, M);

  dim3 grid((M >> 7) * (N >> 7));  // 64 * 32 = 2048
  gemm_dist_kernel<<<grid, 256, 0, stream>>>(xb, wb, xsq, wsq, out, M, N);
}

// Round 10
// 66.888 us; speedup vs baseline: 1.4629x; 1.4629x over previous
//
#include <hip/hip_runtime.h>
#include <hip/hip_bf16.h>

// out[b,w] = relu(sqrt(max(||x_b||^2 + ||w_w||^2 - 2*x_b.w_w, 0)) / sqrt(512))
// M=8192, N=4096, K=512. bf16 MFMA NT-GEMM.
// R6 champion structure exactly (128x128 tile, BK=64, 4 waves, single-buffer
// 32KB LDS, 2 barriers/K-step, gll width 16, T2 XOR-swizzle, XCD swizzle)
// + ONE change: nontemporal epilogue stores. R9 counters showed FETCH 107 MB
// vs 12 MB unique inputs + WRITE 145 MB: the write stream flushes the panels
// out of L3, forcing HBM re-fetch. 'nt' stores keep panels L3-resident.

typedef __bf16 bf16x8 __attribute__((ext_vector_type(8)));
typedef float f32x4 __attribute__((ext_vector_type(4)));

#define K_DIM 512
#define INV_SCALE 0.04419417382415922f  // 1/22.627417

__device__ __forceinline__ ushort f2bf(float f) {
  __hip_bfloat16 h = __float2bfloat16(f);
  return __builtin_bit_cast(ushort, h);
}

// fp32 -> bf16 convert + row sum of squares. One 128-thread block per row.
__global__ __launch_bounds__(128) void convert_kernel(
    const float* __restrict__ x, const float* __restrict__ w,
    ushort* __restrict__ xb, ushort* __restrict__ wb,
    float* __restrict__ xsq, float* __restrict__ wsq, int M) {
  int b = blockIdx.x;
  const float* src; ushort* dst; float* sq; int row;
  if (b < M) { src = x; dst = xb; sq = xsq; row = b; }
  else       { src = w; dst = wb; sq = wsq; row = b - M; }
  int t = threadIdx.x;
  float4 v = reinterpret_cast<const float4*>(src + (size_t)row * K_DIM)[t];
  ushort4 p;
  p.x = f2bf(v.x); p.y = f2bf(v.y); p.z = f2bf(v.z); p.w = f2bf(v.w);
  reinterpret_cast<ushort4*>(dst + (size_t)row * K_DIM)[t] = p;
  float s = v.x * v.x + v.y * v.y + v.z * v.z + v.w * v.w;
#pragma unroll
  for (int o = 32; o > 0; o >>= 1) s += __shfl_down(s, o, 64);
  __shared__ float red[2];
  if ((t & 63) == 0) red[t >> 6] = s;
  __syncthreads();
  if (t == 0) sq[row] = red[0] + red[1];
}

// LDS holds (row, ch) = global(row, ch ^ (row&7)); staging pre-swizzles the
// per-lane global source chunk (linear gll dest), reads XOR with row&7.
// 2-way residual conflict = free (m136).
__global__ void gemm_dist_kernel(
    const ushort* __restrict__ xb, const ushort* __restrict__ wb,
    const float* __restrict__ xsq, const float* __restrict__ wsq,
    float* __restrict__ out, int M, int N) {
  __shared__ ushort Asm[128 * 64];  // 16 KB
  __shared__ ushort Bsm[128 * 64];  // 16 KB

  const int ntN = N >> 7;
  const int nwg = gridDim.x;
  const int bid = blockIdx.x;
  const int swz = ((nwg & 7) == 0) ? ((bid & 7) * (nwg >> 3) + (bid >> 3)) : bid;
  const int tR = swz / ntN;
  const int tC = swz - tR * ntN;

  const int tid = threadIdx.x;
  const int wid = tid >> 6;
  const int lane = tid & 63;
  const int wr = wid >> 1, wc = wid & 1;
  const int l15 = lane & 15, l4 = lane >> 4;

  const int rowA0 = tR << 7;
  const int rowB0 = tC << 7;

  f32x4 acc[4][4] = {};

  // Staging map: wave wid covers tile rows [wid*32, wid*32+32) in 4 calls of
  // 8 rows each; lane l -> row +(l>>3). Source chunk pre-swizzled (l&7)^(l>>3)
  // (row&7 == l>>3 here) so the linear gll dest yields the swizzled layout.
  const int srow = (wid << 5) + (lane >> 3);
  const int scol = ((lane & 7) ^ (lane >> 3)) << 3;
  const ushort* gA = xb + (size_t)(rowA0 + srow) * K_DIM + scol;
  const ushort* gB = wb + (size_t)(rowB0 + srow) * K_DIM + scol;

  for (int kt = 0; kt < K_DIM; kt += 64) {
#pragma unroll
    for (int c = 0; c < 4; ++c) {
      const int r0 = (wid << 5) + (c << 3);  // wave-uniform LDS row base
      __builtin_amdgcn_global_load_lds(
          (const __attribute__((address_space(1))) void*)(gA + (size_t)(c * 8) * K_DIM + kt),
          (__attribute__((address_space(3))) void*)&Asm[r0 * 64], 16, 0, 0);
      __builtin_amdgcn_global_load_lds(
          (const __attribute__((address_space(1))) void*)(gB + (size_t)(c * 8) * K_DIM + kt),
          (__attribute__((address_space(3))) void*)&Bsm[r0 * 64], 16, 0, 0);
    }
    __syncthreads();  // compiler emits vmcnt(0) drain before s_barrier

    const int axor = l15 & 7;  // row&7 for this lane's fragment rows
#pragma unroll
    for (int kk = 0; kk < 2; ++kk) {
      bf16x8 af[4], bfr[4];
      const int cx = (((kk << 2) + l4) ^ axor) << 3;  // swizzled chunk offset
#pragma unroll
      for (int i = 0; i < 4; ++i) {
        af[i]  = *reinterpret_cast<const bf16x8*>(
            &Asm[((wr << 6) + (i << 4) + l15) * 64 + cx]);
        bfr[i] = *reinterpret_cast<const bf16x8*>(
            &Bsm[((wc << 6) + (i << 4) + l15) * 64 + cx]);
      }
#pragma unroll
      for (int i = 0; i < 4; ++i)
#pragma unroll
        for (int j = 0; j < 4; ++j)
          acc[i][j] = __builtin_amdgcn_mfma_f32_16x16x32_bf16(af[i], bfr[j], acc[i][j], 0, 0, 0);
    }
    __syncthreads();
  }

  // Epilogue. C/D mapping: col = lane&15, row = (lane>>4)*4 + reg.
  // Nontemporal stores: output is never re-read; don't let the 134 MB write
  // stream evict the 12 MB A/B panels from L3 (R9: FETCH 107 MB overfetch).
  const int colBase = rowB0 + (wc << 6) + l15;
  const int rowBase = rowA0 + (wr << 6) + (l4 << 2);
  float xq[4][4];
#pragma unroll
  for (int i = 0; i < 4; ++i)
#pragma unroll
    for (int r = 0; r < 4; ++r) xq[i][r] = xsq[rowBase + (i << 4) + r];
  float wq[4];
#pragma unroll
  for (int j = 0; j < 4; ++j) wq[j] = wsq[colBase + (j << 4)];

#pragma unroll
  for (int i = 0; i < 4; ++i) {
#pragma unroll
    for (int r = 0; r < 4; ++r) {
      const size_t rbase = (size_t)(rowBase + (i << 4) + r) * (size_t)N;
#pragma unroll
      for (int j = 0; j < 4; ++j) {
        float v = xq[i][r] + wq[j] - 2.0f * acc[i][j][r];
        v = fmaxf(v, 0.0f);
        __builtin_nontemporal_store(sqrtf(v) * INV_SCALE,
                                    &out[rbase + colBase + (j << 4)]);
      }
    }
  }
}

extern "C" void kernel_launch(void* const* d_in, const int* in_sizes, int n_in,
                              void* d_out, int out_size, void* d_ws, size_t ws_size,
                              hipStream_t stream) {
  const float* x = (const float*)d_in[0];   // (M, 512) fp32
  const float* w = (const float*)d_in[1];   // (N, 512) fp32
  const int M = in_sizes[0] / K_DIM;        // 8192
  const int N = in_sizes[1] / K_DIM;        // 4096
  float* out = (float*)d_out;

  char* ws = (char*)d_ws;
  ushort* xb = (ushort*)ws;
  ushort* wb = (ushort*)(ws + (size_t)M * K_DIM * 2);
  float* xsq = (float*)(ws + (size_t)M * K_DIM * 2 + (size_t)N * K_DIM * 2);
  float* wsq = xsq + M;

  convert_kernel<<<M + N, 128, 0, stream>>>(x, w, xb, wb, xsq, wsq, M);

  dim3 grid((M >> 7) * (N >> 7));  // 64 * 32 = 2048
  gemm_dist_kernel<<<grid, 256, 0, stream>>>(xb, wb, xsq, wsq, out, M, N);
}

// Round 11
// 58.025 us; speedup vs baseline: 1.6864x; 1.1527x over previous
//
#include <hip/hip_runtime.h>
#include <hip/hip_bf16.h>

// out[b,w] = relu(sqrt(max(||x_b||^2 + ||w_w||^2 - 2*x_b.w_w, 0)) / sqrt(512))
// M=8192, N=4096, K=512. bf16 MFMA NT-GEMM.
// R6 champion structure exactly (128x128 tile, BK=64, 4 waves, single-buffer
// 32KB LDS, 2 barriers/K-step, gll width 16, T2 XOR-swizzle, plain stores)
// + ONE change: 2D XCD tile-grouping. The 64x32 tile grid is split into 8
// groups of 16x16 tiles, one per XCD (bid&7). Resident set per XCD: ~6
// A-panels + 16 B-panels = 2.75 MB < 4 MB L2, so panel re-reads hit the
// XCD-private L2 instead of the write-polluted L3/HBM (R9: FETCH 107 MB).

typedef __bf16 bf16x8 __attribute__((ext_vector_type(8)));
typedef float f32x4 __attribute__((ext_vector_type(4)));

#define K_DIM 512
#define INV_SCALE 0.04419417382415922f  // 1/22.627417

__device__ __forceinline__ ushort f2bf(float f) {
  __hip_bfloat16 h = __float2bfloat16(f);
  return __builtin_bit_cast(ushort, h);
}

// fp32 -> bf16 convert + row sum of squares. One 128-thread block per row.
__global__ __launch_bounds__(128) void convert_kernel(
    const float* __restrict__ x, const float* __restrict__ w,
    ushort* __restrict__ xb, ushort* __restrict__ wb,
    float* __restrict__ xsq, float* __restrict__ wsq, int M) {
  int b = blockIdx.x;
  const float* src; ushort* dst; float* sq; int row;
  if (b < M) { src = x; dst = xb; sq = xsq; row = b; }
  else       { src = w; dst = wb; sq = wsq; row = b - M; }
  int t = threadIdx.x;
  float4 v = reinterpret_cast<const float4*>(src + (size_t)row * K_DIM)[t];
  ushort4 p;
  p.x = f2bf(v.x); p.y = f2bf(v.y); p.z = f2bf(v.z); p.w = f2bf(v.w);
  reinterpret_cast<ushort4*>(dst + (size_t)row * K_DIM)[t] = p;
  float s = v.x * v.x + v.y * v.y + v.z * v.z + v.w * v.w;
#pragma unroll
  for (int o = 32; o > 0; o >>= 1) s += __shfl_down(s, o, 64);
  __shared__ float red[2];
  if ((t & 63) == 0) red[t >> 6] = s;
  __syncthreads();
  if (t == 0) sq[row] = red[0] + red[1];
}

// LDS holds (row, ch) = global(row, ch ^ (row&7)); staging pre-swizzles the
// per-lane global source chunk (linear gll dest), reads XOR with row&7.
// 2-way residual conflict = free (m136).
__global__ void gemm_dist_kernel(
    const ushort* __restrict__ xb, const ushort* __restrict__ wb,
    const float* __restrict__ xsq, const float* __restrict__ wsq,
    float* __restrict__ out, int M, int N) {
  __shared__ ushort Asm[128 * 64];  // 16 KB
  __shared__ ushort Bsm[128 * 64];  // 16 KB

  const int ntN = N >> 7;                 // 32
  const int ntM = M >> 7;                 // 64
  const int nwg = gridDim.x;              // 2048
  const int bid = blockIdx.x;
  int tR, tC;
  if (ntM == 64 && ntN == 32 && nwg == 2048) {
    // 2D XCD grouping: 8 groups (4 rows x 2 cols) of 16x16 tiles.
    // xcd = bid&7 (dispatch round-robin), i = bid>>3 row-major within group.
    const int x = bid & 7;
    const int i = bid >> 3;
    tR = ((x >> 1) << 4) + (i >> 4);
    tC = ((x & 1) << 4) + (i & 15);
  } else {
    const int swz = ((nwg & 7) == 0) ? ((bid & 7) * (nwg >> 3) + (bid >> 3)) : bid;
    tR = swz / ntN;
    tC = swz - tR * ntN;
  }

  const int tid = threadIdx.x;
  const int wid = tid >> 6;
  const int lane = tid & 63;
  const int wr = wid >> 1, wc = wid & 1;
  const int l15 = lane & 15, l4 = lane >> 4;

  const int rowA0 = tR << 7;
  const int rowB0 = tC << 7;

  f32x4 acc[4][4] = {};

  // Staging map: wave wid covers tile rows [wid*32, wid*32+32) in 4 calls of
  // 8 rows each; lane l -> row +(l>>3). Source chunk pre-swizzled (l&7)^(l>>3)
  // (row&7 == l>>3 here) so the linear gll dest yields the swizzled layout.
  const int srow = (wid << 5) + (lane >> 3);
  const int scol = ((lane & 7) ^ (lane >> 3)) << 3;
  const ushort* gA = xb + (size_t)(rowA0 + srow) * K_DIM + scol;
  const ushort* gB = wb + (size_t)(rowB0 + srow) * K_DIM + scol;

  for (int kt = 0; kt < K_DIM; kt += 64) {
#pragma unroll
    for (int c = 0; c < 4; ++c) {
      const int r0 = (wid << 5) + (c << 3);  // wave-uniform LDS row base
      __builtin_amdgcn_global_load_lds(
          (const __attribute__((address_space(1))) void*)(gA + (size_t)(c * 8) * K_DIM + kt),
          (__attribute__((address_space(3))) void*)&Asm[r0 * 64], 16, 0, 0);
      __builtin_amdgcn_global_load_lds(
          (const __attribute__((address_space(1))) void*)(gB + (size_t)(c * 8) * K_DIM + kt),
          (__attribute__((address_space(3))) void*)&Bsm[r0 * 64], 16, 0, 0);
    }
    __syncthreads();  // compiler emits vmcnt(0) drain before s_barrier

    const int axor = l15 & 7;  // row&7 for this lane's fragment rows
#pragma unroll
    for (int kk = 0; kk < 2; ++kk) {
      bf16x8 af[4], bfr[4];
      const int cx = (((kk << 2) + l4) ^ axor) << 3;  // swizzled chunk offset
#pragma unroll
      for (int i = 0; i < 4; ++i) {
        af[i]  = *reinterpret_cast<const bf16x8*>(
            &Asm[((wr << 6) + (i << 4) + l15) * 64 + cx]);
        bfr[i] = *reinterpret_cast<const bf16x8*>(
            &Bsm[((wc << 6) + (i << 4) + l15) * 64 + cx]);
      }
#pragma unroll
      for (int i = 0; i < 4; ++i)
#pragma unroll
        for (int j = 0; j < 4; ++j)
          acc[i][j] = __builtin_amdgcn_mfma_f32_16x16x32_bf16(af[i], bfr[j], acc[i][j], 0, 0, 0);
    }
    __syncthreads();
  }

  // Epilogue. C/D mapping: col = lane&15, row = (lane>>4)*4 + reg.
  const int colBase = rowB0 + (wc << 6) + l15;
  const int rowBase = rowA0 + (wr << 6) + (l4 << 2);
  float xq[4][4];
#pragma unroll
  for (int i = 0; i < 4; ++i)
#pragma unroll
    for (int r = 0; r < 4; ++r) xq[i][r] = xsq[rowBase + (i << 4) + r];
  float wq[4];
#pragma unroll
  for (int j = 0; j < 4; ++j) wq[j] = wsq[colBase + (j << 4)];

#pragma unroll
  for (int i = 0; i < 4; ++i) {
#pragma unroll
    for (int r = 0; r < 4; ++r) {
      const size_t rbase = (size_t)(rowBase + (i << 4) + r) * (size_t)N;
#pragma unroll
      for (int j = 0; j < 4; ++j) {
        float v = xq[i][r] + wq[j] - 2.0f * acc[i][j][r];
        v = fmaxf(v, 0.0f);
        out[rbase + colBase + (j << 4)] = sqrtf(v) * INV_SCALE;
      }
    }
  }
}

extern "C" void kernel_launch(void* const* d_in, const int* in_sizes, int n_in,
                              void* d_out, int out_size, void* d_ws, size_t ws_size,
                              hipStream_t stream) {
  const float* x = (const float*)d_in[0];   // (M, 512) fp32
  const float* w = (const float*)d_in[1];   // (N, 512) fp32
  const int M = in_sizes[0] / K_DIM;        // 8192
  const int N = in_sizes[1] / K_DIM;        // 4096
  float* out = (float*)d_out;

  char* ws = (char*)d_ws;
  ushort* xb = (ushort*)ws;
  ushort* wb = (ushort*)(ws + (size_t)M * K_DIM * 2);
  float* xsq = (float*)(ws + (size_t)M * K_DIM * 2 + (size_t)N * K_DIM * 2);
  float* wsq = xsq + M;

  convert_kernel<<<M + N, 128, 0, stream>>>(x, w, xb, wb, xsq, wsq, M);

  dim3 grid((M >> 7) * (N >> 7));  // 64 * 32 = 2048
  gemm_dist_kernel<<<grid, 256, 0, stream>>>(xb, wb, xsq, wsq, out, M, N);
}